// Round 6
// baseline (208.888 us; speedup 1.0000x reference)
//
#include <hip/hip_runtime.h>
#include <hip/hip_bf16.h>

#define NTOT 8192   // 2B
#define BB   4096   // B
#define DD   256    // D
#define NSTRIPE 32  // column stripes (gridDim.y)

typedef __attribute__((ext_vector_type(8))) short short8v;  // 8 bf16 = 4 VGPR
typedef __attribute__((ext_vector_type(4))) float f32x4;

__device__ __forceinline__ unsigned short f2bf(float f) {
    union { __hip_bfloat16 h; unsigned short u; } cv;
    cv.h = __float2bfloat16(f);
    return cv.u;
}

// One wave per pair r: normalize x1[r], x2[r]; emit bf16 z rows r and r+BB;
// fp32 selfdot (z.z) and posdot (z1.z2). Block 0 zeroes out[0] for k_final.
__global__ __launch_bounds__(256) void k_normalize(
    const float* __restrict__ x1, const float* __restrict__ x2,
    unsigned short* __restrict__ zbf,
    float* __restrict__ selfdot, float* __restrict__ posdot,
    float* __restrict__ out)
{
    if (blockIdx.x == 0 && threadIdx.x == 0) out[0] = 0.0f;

    const int lane = threadIdx.x & 63;
    const int pair = blockIdx.x * 4 + (threadIdx.x >> 6);

    const float4 a = *(const float4*)(x1 + (size_t)pair * DD + lane * 4);
    const float4 b = *(const float4*)(x2 + (size_t)pair * DD + lane * 4);

    float s1 = a.x * a.x + a.y * a.y + a.z * a.z + a.w * a.w;
    float s2 = b.x * b.x + b.y * b.y + b.z * b.z + b.w * b.w;
#pragma unroll
    for (int off = 1; off < 64; off <<= 1) {
        s1 += __shfl_xor(s1, off);
        s2 += __shfl_xor(s2, off);
    }
    const float inv1 = 1.0f / fmaxf(sqrtf(s1), 1e-12f);
    const float inv2 = 1.0f / fmaxf(sqrtf(s2), 1e-12f);

    const float4 z1 = make_float4(a.x * inv1, a.y * inv1, a.z * inv1, a.w * inv1);
    const float4 z2 = make_float4(b.x * inv2, b.y * inv2, b.z * inv2, b.w * inv2);

    float sd1 = z1.x * z1.x + z1.y * z1.y + z1.z * z1.z + z1.w * z1.w;
    float sd2 = z2.x * z2.x + z2.y * z2.y + z2.z * z2.z + z2.w * z2.w;
    float pd  = z1.x * z2.x + z1.y * z2.y + z1.z * z2.z + z1.w * z2.w;
#pragma unroll
    for (int off = 1; off < 64; off <<= 1) {
        sd1 += __shfl_xor(sd1, off);
        sd2 += __shfl_xor(sd2, off);
        pd  += __shfl_xor(pd, off);
    }

    ushort4 u1, u2;
    u1.x = f2bf(z1.x); u1.y = f2bf(z1.y); u1.z = f2bf(z1.z); u1.w = f2bf(z1.w);
    u2.x = f2bf(z2.x); u2.y = f2bf(z2.y); u2.z = f2bf(z2.z); u2.w = f2bf(z2.w);
    *(ushort4*)(zbf + (size_t)pair * DD + lane * 4) = u1;
    *(ushort4*)(zbf + (size_t)(pair + BB) * DD + lane * 4) = u2;

    if (lane == 0) {
        selfdot[pair] = sd1;
        selfdot[pair + BB] = sd2;
        posdot[pair] = pd;
        posdot[pair + BB] = pd;
    }
}

// OCCUPANCY RESTRUCTURE (round 6): 32 rows/wave (Afrag[2][8] = 64 VGPR) and
// 2 x 16 KB LDS buffers (32-col steps) so 4 blocks/CU x 4 waves = 16 waves/CU
// fit (was 2 blocks / 8 waves, Occupancy 18%; rounds 4-5 proved inner-loop
// scheduling is not the bottleneck -- too few waves to hide ds_read latency,
// exp VALU, and barrier drains). __launch_bounds__(256,4) caps combined regs
// at 128 (est. demand ~115). Block = 128 rows; stripe = 256 cols = 8 steps of
// 32 cols; grid 64x32 = 2048 blocks (8/CU, multi-round). Staging: linear-dest
// global_load_lds with pre-swizzled source (G21); reads XOR the same mask.
__global__ __launch_bounds__(256, 4) void k_simsum(
    const unsigned short* __restrict__ zbf, float* __restrict__ S_part)
{
    __shared__ char Bsh[2][16384];   // 2 x (32 cols x 512 B) = 32 KB

    const int tid  = threadIdx.x;
    const int lane = tid & 63;
    const int wave = tid >> 6;
    const int frow = lane & 15;
    const int row0 = blockIdx.x * 128 + wave * 32;
    const int colStart = blockIdx.y * 256;

    // ---- A: 32 rows x 256 k in registers (64 VGPR) ----
    short8v Afrag[2][8];
#pragma unroll
    for (int rt = 0; rt < 2; ++rt) {
        const int row = row0 + rt * 16 + frow;
        const unsigned short* ap = zbf + (size_t)row * DD + (lane >> 4) * 8;
#pragma unroll
        for (int kk = 0; kk < 8; ++kk)
            Afrag[rt][kk] = *(const short8v*)(ap + kk * 32);
    }

    // Staging: pre-swizzled source offset; LDS dest linear (G21 rule).
    const int jswz = (tid & 31) ^ ((tid >> 5) & 7);
    const char* gsrc0 = (const char*)zbf + (size_t)colStart * 512
                        + (tid >> 5) * 512 + jswz * 16;

    // Read addrs: (base0 + kk*64) ^ bmask; base0 bits {4-5,9-12}, kk*64 bits
    // {6-8}, mask bits {4-6} -> carry-free; b1 = +8192 (bit 13) < 16 KB.
    const int base0 = frow * 512 + (lane >> 4) * 16;
    const int bmask = (frow & 7) << 4;
    int addrs[8];
#pragma unroll
    for (int kk = 0; kk < 8; ++kk) addrs[kk] = (base0 + kk * 64) ^ bmask;

    float rs[2][4];
#pragma unroll
    for (int rt = 0; rt < 2; ++rt)
#pragma unroll
        for (int q = 0; q < 4; ++q) rs[rt][q] = 0.0f;

    // prologue: stage step 0 into buffer 0 (16 KB = 4 rounds x 256 thr x 16 B)
#pragma unroll
    for (int r = 0; r < 4; ++r)
        __builtin_amdgcn_global_load_lds(
            (const __attribute__((address_space(1))) unsigned int*)(gsrc0 + r * 4096),
            (__attribute__((address_space(3))) unsigned int*)(&Bsh[0][0] + tid * 16 + r * 4096),
            16, 0, 0);
    __syncthreads();

    int cur = 0;
    for (int t = 0; t < 8; ++t) {
        if (t < 7) {
            const char* gs = gsrc0 + (size_t)(t + 1) * 16384;
            char* ld = &Bsh[cur ^ 1][0] + tid * 16;
#pragma unroll
            for (int r = 0; r < 4; ++r)
                __builtin_amdgcn_global_load_lds(
                    (const __attribute__((address_space(1))) unsigned int*)(gs + r * 4096),
                    (__attribute__((address_space(3))) unsigned int*)(ld + r * 4096),
                    16, 0, 0);
        }

        const char* bc = &Bsh[cur][0];
        f32x4 acc[2][2];
#pragma unroll
        for (int rt = 0; rt < 2; ++rt)
#pragma unroll
            for (int c = 0; c < 2; ++c) {
                acc[rt][c][0] = 0.0f; acc[rt][c][1] = 0.0f;
                acc[rt][c][2] = 0.0f; acc[rt][c][3] = 0.0f;
            }

#pragma unroll
        for (int kk = 0; kk < 8; ++kk) {
            const short8v b0 = *(const short8v*)(bc + addrs[kk]);
            const short8v b1 = *(const short8v*)(bc + addrs[kk] + 8192);
#pragma unroll
            for (int rt = 0; rt < 2; ++rt) {
                acc[rt][0] = __builtin_amdgcn_mfma_f32_16x16x32_bf16(
                    Afrag[rt][kk], b0, acc[rt][0], 0, 0, 0);
                acc[rt][1] = __builtin_amdgcn_mfma_f32_16x16x32_bf16(
                    Afrag[rt][kk], b1, acc[rt][1], 0, 0, 0);
            }
        }

#pragma unroll
        for (int rt = 0; rt < 2; ++rt)
#pragma unroll
            for (int q = 0; q < 4; ++q)
                rs[rt][q] += exp2f(acc[rt][0][q] * 2.8853900817779268f)
                           + exp2f(acc[rt][1][q] * 2.8853900817779268f);

        __syncthreads();   // drains staged loads + protects buffer reuse
        cur ^= 1;
    }

    // C layout: col = lane&15, row = (lane>>4)*4 + q. Reduce over the 16 cols.
#pragma unroll
    for (int rt = 0; rt < 2; ++rt) {
#pragma unroll
        for (int q = 0; q < 4; ++q) {
            float v = rs[rt][q];
            v += __shfl_xor(v, 1);
            v += __shfl_xor(v, 2);
            v += __shfl_xor(v, 4);
            v += __shfl_xor(v, 8);
            if (frow == 0) {
                const int row = row0 + rt * 16 + (lane >> 4) * 4 + q;
                S_part[blockIdx.y * NTOT + row] = v;
            }
        }
    }
}

// 32 blocks x 256 threads: each thread one row. Combine 32 partials, subtract
// fp32 diagonal, log, subtract numerator (= 2*posdot); block-reduce; atomicAdd.
__global__ __launch_bounds__(256) void k_final(
    const float* __restrict__ S_part, const float* __restrict__ selfdot,
    const float* __restrict__ posdot, float* __restrict__ out)
{
    __shared__ float red[4];
    const int tid = threadIdx.x;
    const int i = blockIdx.x * 256 + tid;
    float s = 0.0f;
#pragma unroll
    for (int sp = 0; sp < NSTRIPE; ++sp) s += S_part[sp * NTOT + i];
    const float den = fmaxf(s - expf(2.0f * selfdot[i]), 1e-8f);
    float acc = logf(den) - 2.0f * posdot[i];
#pragma unroll
    for (int off = 1; off < 64; off <<= 1) acc += __shfl_xor(acc, off);
    if ((tid & 63) == 0) red[tid >> 6] = acc;
    __syncthreads();
    if (tid == 0)
        atomicAdd(out, (red[0] + red[1] + red[2] + red[3]) * (1.0f / (float)NTOT));
}

extern "C" void kernel_launch(void* const* d_in, const int* in_sizes, int n_in,
                              void* d_out, int out_size, void* d_ws, size_t ws_size,
                              hipStream_t stream) {
    const float* x1 = (const float*)d_in[0];
    const float* x2 = (const float*)d_in[1];
    float* out = (float*)d_out;

    char* ws = (char*)d_ws;
    unsigned short* zbf = (unsigned short*)ws;                       // 4 MB
    size_t off = (size_t)NTOT * DD * sizeof(unsigned short);
    float* S_part = (float*)(ws + off);                              // 32*8192*4 = 1 MB
    off += (size_t)NSTRIPE * NTOT * sizeof(float);
    float* selfdot = (float*)(ws + off);                             // 32 KB
    off += (size_t)NTOT * sizeof(float);
    float* posdot = (float*)(ws + off);                              // 32 KB

    k_normalize<<<dim3(BB / 4), dim3(256), 0, stream>>>(x1, x2, zbf, selfdot, posdot, out);
    k_simsum<<<dim3(64, NSTRIPE), dim3(256), 0, stream>>>(zbf, S_part);
    k_final<<<dim3(NTOT / 256), dim3(256), 0, stream>>>(S_part, selfdot, posdot, out);
}

// Round 7
// 139.688 us; speedup vs baseline: 1.4954x; 1.4954x over previous
//
#include <hip/hip_runtime.h>
#include <hip/hip_bf16.h>

#define NTOT 8192   // 2B
#define BB   4096   // B
#define DD   256    // D
#define NSTRIPE 16  // column stripes (gridDim.y)

typedef __attribute__((ext_vector_type(8))) short short8v;  // 8 bf16 = 4 VGPR
typedef __attribute__((ext_vector_type(4))) float f32x4;

__device__ __forceinline__ unsigned short f2bf(float f) {
    union { __hip_bfloat16 h; unsigned short u; } cv;
    cv.h = __float2bfloat16(f);
    return cv.u;
}

// One wave per pair r: normalize x1[r], x2[r]; emit bf16 z rows r and r+BB;
// fp32 selfdot (z.z) and posdot (z1.z2). Block 0 zeroes out[0] for k_final.
__global__ __launch_bounds__(256) void k_normalize(
    const float* __restrict__ x1, const float* __restrict__ x2,
    unsigned short* __restrict__ zbf,
    float* __restrict__ selfdot, float* __restrict__ posdot,
    float* __restrict__ out)
{
    if (blockIdx.x == 0 && threadIdx.x == 0) out[0] = 0.0f;

    const int lane = threadIdx.x & 63;
    const int pair = blockIdx.x * 4 + (threadIdx.x >> 6);

    const float4 a = *(const float4*)(x1 + (size_t)pair * DD + lane * 4);
    const float4 b = *(const float4*)(x2 + (size_t)pair * DD + lane * 4);

    float s1 = a.x * a.x + a.y * a.y + a.z * a.z + a.w * a.w;
    float s2 = b.x * b.x + b.y * b.y + b.z * b.z + b.w * b.w;
#pragma unroll
    for (int off = 1; off < 64; off <<= 1) {
        s1 += __shfl_xor(s1, off);
        s2 += __shfl_xor(s2, off);
    }
    const float inv1 = 1.0f / fmaxf(sqrtf(s1), 1e-12f);
    const float inv2 = 1.0f / fmaxf(sqrtf(s2), 1e-12f);

    const float4 z1 = make_float4(a.x * inv1, a.y * inv1, a.z * inv1, a.w * inv1);
    const float4 z2 = make_float4(b.x * inv2, b.y * inv2, b.z * inv2, b.w * inv2);

    float sd1 = z1.x * z1.x + z1.y * z1.y + z1.z * z1.z + z1.w * z1.w;
    float sd2 = z2.x * z2.x + z2.y * z2.y + z2.z * z2.z + z2.w * z2.w;
    float pd  = z1.x * z2.x + z1.y * z2.y + z1.z * z2.z + z1.w * z2.w;
#pragma unroll
    for (int off = 1; off < 64; off <<= 1) {
        sd1 += __shfl_xor(sd1, off);
        sd2 += __shfl_xor(sd2, off);
        pd  += __shfl_xor(pd, off);
    }

    ushort4 u1, u2;
    u1.x = f2bf(z1.x); u1.y = f2bf(z1.y); u1.z = f2bf(z1.z); u1.w = f2bf(z1.w);
    u2.x = f2bf(z2.x); u2.y = f2bf(z2.y); u2.z = f2bf(z2.z); u2.w = f2bf(z2.w);
    *(ushort4*)(zbf + (size_t)pair * DD + lane * 4) = u1;
    *(ushort4*)(zbf + (size_t)(pair + BB) * DD + lane * 4) = u2;

    if (lane == 0) {
        selfdot[pair] = sd1;
        selfdot[pair + BB] = sd2;
        posdot[pair] = pd;
        posdot[pair + BB] = pd;
    }
}

// BARRIER-FREE direct-load GEMM (round 7). Rounds 3-6 showed the LDS-staged
// block-synchronous structure idles ~65% of issue slots at 2 waves/SIMD
// (barrier+vmcnt drain lockstep; m233 regime), and reg-capping to raise
// occupancy spills catastrophically. Here: NO LDS, NO __syncthreads. Each
// wave owns 64 rows (A resident: Afrag[4][8] = 128 regs) and sweeps a
// 512-col stripe in 32-col chunks, loading B-fragments DIRECTLY from global
// (z is L2-resident: 4 MB/XCD; default bx->XCD mapping gives full A-reuse
// and 4x B-stripe reuse per XCD L2). Per chunk: 16 dwordx4 loads + 64 MFMA,
// no sync anywhere -- scheduler + 2 waves/SIMD overlap freely (MFMA-ubench
// regime). exp(sim/T) = exp2(sim * 2/ln2) folded into per-lane row sums.
__global__ __launch_bounds__(256, 2) void k_simsum(
    const unsigned short* __restrict__ zbf, float* __restrict__ S_part)
{
    const int tid  = threadIdx.x;
    const int lane = tid & 63;
    const int wave = tid >> 6;
    const int frow = lane & 15;
    const int khalf = (lane >> 4) * 8;   // element offset within k-group
    const int row0 = blockIdx.x * 256 + wave * 64;
    const int colStart = blockIdx.y * 512;

    // ---- A: 64 rows x 256 k in registers ----
    short8v Afrag[4][8];
#pragma unroll
    for (int rt = 0; rt < 4; ++rt) {
        const unsigned short* ap = zbf + (size_t)(row0 + rt * 16 + frow) * DD + khalf;
#pragma unroll
        for (int kk = 0; kk < 8; ++kk)
            Afrag[rt][kk] = *(const short8v*)(ap + kk * 32);
    }

    float rs[4][4];
#pragma unroll
    for (int rt = 0; rt < 4; ++rt)
#pragma unroll
        for (int q = 0; q < 4; ++q) rs[rt][q] = 0.0f;

#pragma unroll 2
    for (int ch = 0; ch < 16; ++ch) {
        // B fragments for cols [colStart+ch*32, +32): same per-lane pattern as
        // A (col = frow within each 16-col half, k-sub = khalf).
        const unsigned short* bp = zbf
            + (size_t)(colStart + ch * 32 + frow) * DD + khalf;

        f32x4 acc[4][2];
#pragma unroll
        for (int rt = 0; rt < 4; ++rt)
#pragma unroll
            for (int c = 0; c < 2; ++c) {
                acc[rt][c][0] = 0.0f; acc[rt][c][1] = 0.0f;
                acc[rt][c][2] = 0.0f; acc[rt][c][3] = 0.0f;
            }

#pragma unroll
        for (int kk = 0; kk < 8; ++kk) {
            const short8v b0 = *(const short8v*)(bp + kk * 32);
            const short8v b1 = *(const short8v*)(bp + 16 * DD + kk * 32);
#pragma unroll
            for (int rt = 0; rt < 4; ++rt) {
                acc[rt][0] = __builtin_amdgcn_mfma_f32_16x16x32_bf16(
                    Afrag[rt][kk], b0, acc[rt][0], 0, 0, 0);
                acc[rt][1] = __builtin_amdgcn_mfma_f32_16x16x32_bf16(
                    Afrag[rt][kk], b1, acc[rt][1], 0, 0, 0);
            }
        }

#pragma unroll
        for (int rt = 0; rt < 4; ++rt)
#pragma unroll
            for (int q = 0; q < 4; ++q)
                rs[rt][q] += exp2f(acc[rt][0][q] * 2.8853900817779268f)
                           + exp2f(acc[rt][1][q] * 2.8853900817779268f);
    }

    // C layout: col = lane&15, row = (lane>>4)*4 + q. Reduce over the 16 cols.
#pragma unroll
    for (int rt = 0; rt < 4; ++rt) {
#pragma unroll
        for (int q = 0; q < 4; ++q) {
            float v = rs[rt][q];
            v += __shfl_xor(v, 1);
            v += __shfl_xor(v, 2);
            v += __shfl_xor(v, 4);
            v += __shfl_xor(v, 8);
            if (frow == 0) {
                const int row = row0 + rt * 16 + (lane >> 4) * 4 + q;
                S_part[blockIdx.y * NTOT + row] = v;
            }
        }
    }
}

// 32 blocks x 256 threads: each thread one row. Combine 16 partials, subtract
// fp32 diagonal, log, subtract numerator (= 2*posdot); block-reduce; atomicAdd.
__global__ __launch_bounds__(256) void k_final(
    const float* __restrict__ S_part, const float* __restrict__ selfdot,
    const float* __restrict__ posdot, float* __restrict__ out)
{
    __shared__ float red[4];
    const int tid = threadIdx.x;
    const int i = blockIdx.x * 256 + tid;
    float s = 0.0f;
#pragma unroll
    for (int sp = 0; sp < NSTRIPE; ++sp) s += S_part[sp * NTOT + i];
    const float den = fmaxf(s - expf(2.0f * selfdot[i]), 1e-8f);
    float acc = logf(den) - 2.0f * posdot[i];
#pragma unroll
    for (int off = 1; off < 64; off <<= 1) acc += __shfl_xor(acc, off);
    if ((tid & 63) == 0) red[tid >> 6] = acc;
    __syncthreads();
    if (tid == 0)
        atomicAdd(out, (red[0] + red[1] + red[2] + red[3]) * (1.0f / (float)NTOT));
}

extern "C" void kernel_launch(void* const* d_in, const int* in_sizes, int n_in,
                              void* d_out, int out_size, void* d_ws, size_t ws_size,
                              hipStream_t stream) {
    const float* x1 = (const float*)d_in[0];
    const float* x2 = (const float*)d_in[1];
    float* out = (float*)d_out;

    char* ws = (char*)d_ws;
    unsigned short* zbf = (unsigned short*)ws;                       // 4 MB
    size_t off = (size_t)NTOT * DD * sizeof(unsigned short);
    float* S_part = (float*)(ws + off);                              // 16*8192*4 = 512 KB
    off += (size_t)NSTRIPE * NTOT * sizeof(float);
    float* selfdot = (float*)(ws + off);                             // 32 KB
    off += (size_t)NTOT * sizeof(float);
    float* posdot = (float*)(ws + off);                              // 32 KB

    k_normalize<<<dim3(BB / 4), dim3(256), 0, stream>>>(x1, x2, zbf, selfdot, posdot, out);
    k_simsum<<<dim3(32, NSTRIPE), dim3(256), 0, stream>>>(zbf, S_part);
    k_final<<<dim3(NTOT / 256), dim3(256), 0, stream>>>(S_part, selfdot, posdot, out);
}

// Round 8
// 100.619 us; speedup vs baseline: 2.0760x; 1.3883x over previous
//
#include <hip/hip_runtime.h>
#include <hip/hip_bf16.h>

#define NTOT 8192   // 2B
#define BB   4096   // B
#define DD   256    // D
#define NBLK 512    // k_simsum grid (2 blocks/CU exactly)
#define NSTEPS 2112 // triangle steps: sum_i (128 - 4i), i<32

typedef __attribute__((ext_vector_type(8))) short short8v;  // 8 bf16 = 4 VGPR
typedef __attribute__((ext_vector_type(4))) float f32x4;

__device__ __forceinline__ unsigned short f2bf(float f) {
    union { __hip_bfloat16 h; unsigned short u; } cv;
    cv.h = __float2bfloat16(f);
    return cv.u;
}

// One wave per pair r: normalize x1[r], x2[r]; emit bf16 z rows r and r+BB;
// fp32 selfdot (z.z) and posdot (z1.z2). Blocks 0-7 zero S; block 0 zeros out.
__global__ __launch_bounds__(256) void k_normalize(
    const float* __restrict__ x1, const float* __restrict__ x2,
    unsigned short* __restrict__ zbf,
    float* __restrict__ selfdot, float* __restrict__ posdot,
    float* __restrict__ S, float* __restrict__ out)
{
    if (blockIdx.x < 8) {
        float4 z4 = make_float4(0.f, 0.f, 0.f, 0.f);
        *(float4*)(S + blockIdx.x * 1024 + threadIdx.x * 4) = z4;
        if (blockIdx.x == 0 && threadIdx.x == 0) out[0] = 0.0f;
    }

    const int lane = threadIdx.x & 63;
    const int pair = blockIdx.x * 4 + (threadIdx.x >> 6);

    const float4 a = *(const float4*)(x1 + (size_t)pair * DD + lane * 4);
    const float4 b = *(const float4*)(x2 + (size_t)pair * DD + lane * 4);

    float s1 = a.x * a.x + a.y * a.y + a.z * a.z + a.w * a.w;
    float s2 = b.x * b.x + b.y * b.y + b.z * b.z + b.w * b.w;
#pragma unroll
    for (int off = 1; off < 64; off <<= 1) {
        s1 += __shfl_xor(s1, off);
        s2 += __shfl_xor(s2, off);
    }
    const float inv1 = 1.0f / fmaxf(sqrtf(s1), 1e-12f);
    const float inv2 = 1.0f / fmaxf(sqrtf(s2), 1e-12f);

    const float4 z1 = make_float4(a.x * inv1, a.y * inv1, a.z * inv1, a.w * inv1);
    const float4 z2 = make_float4(b.x * inv2, b.y * inv2, b.z * inv2, b.w * inv2);

    float sd1 = z1.x * z1.x + z1.y * z1.y + z1.z * z1.z + z1.w * z1.w;
    float sd2 = z2.x * z2.x + z2.y * z2.y + z2.z * z2.z + z2.w * z2.w;
    float pd  = z1.x * z2.x + z1.y * z2.y + z1.z * z2.z + z1.w * z2.w;
#pragma unroll
    for (int off = 1; off < 64; off <<= 1) {
        sd1 += __shfl_xor(sd1, off);
        sd2 += __shfl_xor(sd2, off);
        pd  += __shfl_xor(pd, off);
    }

    ushort4 u1, u2;
    u1.x = f2bf(z1.x); u1.y = f2bf(z1.y); u1.z = f2bf(z1.z); u1.w = f2bf(z1.w);
    u2.x = f2bf(z2.x); u2.y = f2bf(z2.y); u2.z = f2bf(z2.z); u2.w = f2bf(z2.w);
    *(ushort4*)(zbf + (size_t)pair * DD + lane * 4) = u1;
    *(ushort4*)(zbf + (size_t)(pair + BB) * DD + lane * 4) = u2;

    if (lane == 0) {
        selfdot[pair] = sd1;
        selfdot[pair + BB] = sd2;
        posdot[pair] = pd;
        posdot[pair + BB] = pd;
    }
}

// SYMMETRY-HALVED triangle GEMM (round 8). exp(2*z z^T) is symmetric: compute
// only diagonal-square + strictly-upper 64-col steps per 256-row tile; upper
// steps credit BOTH row sums (in-reg, flushed via atomicAdd) and column sums
// (per-wave shfl reduce over rows + atomicAdd). Row-tile i owns 128-4i steps
// (4 diag + 124-4i upper); all 2112 steps are flattened and block b in [0,512)
// takes steps [33b/8, 33(b+1)/8) -> 4-5 steps each, 2 blocks/CU, single
// balanced round (no triangle tail). Inner core = proven round-3 structure:
// global_load_lds width-16 dbuf staging with pre-swizzled source (G21),
// XOR-swizzled ds_read_b128, A-in-regs, one barrier per step.
__global__ __launch_bounds__(256, 2) void k_simsum(
    const unsigned short* __restrict__ zbf, float* __restrict__ S)
{
    __shared__ char Bsh[2][32768];   // 2 x (64 cols x 512 B), 64 KB

    const int tid  = threadIdx.x;
    const int lane = tid & 63;
    const int wave = tid >> 6;
    const int frow = lane & 15;

    const int b = blockIdx.x;
    const int sBeg = (33 * b) >> 3;
    const int sEnd = (33 * (b + 1)) >> 3;

    // decode step sBeg -> (row-tile i, step-in-tile t); tile i has 128-4i steps
    int ai = 0;
    {
        int C = 0;
        while (C + 128 - 4 * ai <= sBeg) { C += 128 - 4 * ai; ++ai; }
        // t for first step:
        // (kept implicitly below via ct)
    }
    int C2 = 0;
    for (int k = 0; k < ai; ++k) C2 += 128 - 4 * k;
    int ct = sBeg - C2;

    // staging: pre-swizzled source offset; LDS dest linear (G21 rule)
    const int jswz = (tid & 31) ^ ((tid >> 5) & 7);
    const int stageOff = (tid >> 5) * 512 + jswz * 16;

    // ds_read swizzled addresses (carry-free XOR; proven round-3)
    const int base0 = frow * 512 + (lane >> 4) * 16;
    const int bmask = (frow & 7) << 4;
    int addrs[8];
#pragma unroll
    for (int kk = 0; kk < 8; ++kk) addrs[kk] = (base0 + kk * 64) ^ bmask;

    // ---- A: 64 rows x 256 k in registers for row-tile ai ----
    short8v Afrag[4][8];
#pragma unroll
    for (int rt = 0; rt < 4; ++rt) {
        const unsigned short* ap =
            zbf + (size_t)(256 * ai + wave * 64 + rt * 16 + frow) * DD + (lane >> 4) * 8;
#pragma unroll
        for (int kk = 0; kk < 8; ++kk)
            Afrag[rt][kk] = *(const short8v*)(ap + kk * 32);
    }

    float rs[4][4];
#pragma unroll
    for (int rt = 0; rt < 4; ++rt)
#pragma unroll
        for (int q = 0; q < 4; ++q) rs[rt][q] = 0.0f;

#define COLBASE(ii, tt) ((tt) < 4 ? 256 * (ii) + 64 * (tt) : 256 * ((ii) + 1) + 64 * ((tt) - 4))

#define STAGE(cb, bufidx)                                                          \
    do {                                                                           \
        const char* gs_ = (const char*)zbf + (size_t)(cb) * 512 + stageOff;        \
        char* ld_ = &Bsh[bufidx][0] + tid * 16;                                    \
        _Pragma("unroll")                                                          \
        for (int r_ = 0; r_ < 8; ++r_)                                             \
            __builtin_amdgcn_global_load_lds(                                      \
                (const __attribute__((address_space(1))) unsigned int*)(gs_ + r_ * 4096), \
                (__attribute__((address_space(3))) unsigned int*)(ld_ + r_ * 4096),\
                16, 0, 0);                                                         \
    } while (0)

    // prologue: stage first step into buffer 0
    STAGE(COLBASE(ai, ct), 0);
    __syncthreads();

    int cur = 0;
    int ci = ai, cstep = ct;
    for (int s = sBeg; s < sEnd; ++s) {
        // decode next step
        int ni = ci, nt = cstep + 1;
        if (nt >= 128 - 4 * ci) { ni = ci + 1; nt = 0; }
        if (s + 1 < sEnd) STAGE(COLBASE(ni, nt), cur ^ 1);

        const int  colbase = COLBASE(ci, cstep);
        const bool isUpper = (cstep >= 4);
        const char* bsh = &Bsh[cur][0];

#pragma unroll
        for (int c2 = 0; c2 < 2; ++c2) {
            const char* bc = bsh + c2 * 16384;
            f32x4 acc[4][2];
#pragma unroll
            for (int rt = 0; rt < 4; ++rt)
#pragma unroll
                for (int c = 0; c < 2; ++c) {
                    acc[rt][c][0] = 0.0f; acc[rt][c][1] = 0.0f;
                    acc[rt][c][2] = 0.0f; acc[rt][c][3] = 0.0f;
                }

#pragma unroll
            for (int kk = 0; kk < 8; ++kk) {
                const short8v b0 = *(const short8v*)(bc + addrs[kk]);
                const short8v b1 = *(const short8v*)(bc + addrs[kk] + 8192);
#pragma unroll
                for (int rt = 0; rt < 4; ++rt) {
                    acc[rt][0] = __builtin_amdgcn_mfma_f32_16x16x32_bf16(
                        Afrag[rt][kk], b0, acc[rt][0], 0, 0, 0);
                    acc[rt][1] = __builtin_amdgcn_mfma_f32_16x16x32_bf16(
                        Afrag[rt][kk], b1, acc[rt][1], 0, 0, 0);
                }
            }

            float cs0 = 0.0f, cs1 = 0.0f;
#pragma unroll
            for (int rt = 0; rt < 4; ++rt)
#pragma unroll
                for (int q = 0; q < 4; ++q) {
                    const float e0 = exp2f(acc[rt][0][q] * 2.8853900817779268f);
                    const float e1 = exp2f(acc[rt][1][q] * 2.8853900817779268f);
                    rs[rt][q] += e0 + e1;
                    cs0 += e0; cs1 += e1;
                }
            if (isUpper) {
                // column sums over this wave's 64 rows: reduce across the 4
                // row-groups (lane>>4), then one atomic per column from lanes 0-15
                cs0 += __shfl_xor(cs0, 16); cs0 += __shfl_xor(cs0, 32);
                cs1 += __shfl_xor(cs1, 16); cs1 += __shfl_xor(cs1, 32);
                if (lane < 16) {
                    atomicAdd(&S[colbase + c2 * 32 + frow], cs0);
                    atomicAdd(&S[colbase + c2 * 32 + 16 + frow], cs1);
                }
            }
        }

        // row-tile change: flush row sums, reload A
        if (s + 1 < sEnd && ni != ai) {
#pragma unroll
            for (int rt = 0; rt < 4; ++rt)
#pragma unroll
                for (int q = 0; q < 4; ++q) {
                    float v = rs[rt][q];
                    v += __shfl_xor(v, 1);
                    v += __shfl_xor(v, 2);
                    v += __shfl_xor(v, 4);
                    v += __shfl_xor(v, 8);
                    if (frow == 0)
                        atomicAdd(&S[256 * ai + wave * 64 + rt * 16 + (lane >> 4) * 4 + q], v);
                    rs[rt][q] = 0.0f;
                }
            ai = ni;
#pragma unroll
            for (int rt = 0; rt < 4; ++rt) {
                const unsigned short* ap =
                    zbf + (size_t)(256 * ai + wave * 64 + rt * 16 + frow) * DD + (lane >> 4) * 8;
#pragma unroll
                for (int kk = 0; kk < 8; ++kk)
                    Afrag[rt][kk] = *(const short8v*)(ap + kk * 32);
            }
        }
        ci = ni; cstep = nt;

        __syncthreads();   // staged loads complete + buffer reuse safe
        cur ^= 1;
    }

    // final row-sum flush for tile ai
#pragma unroll
    for (int rt = 0; rt < 4; ++rt)
#pragma unroll
        for (int q = 0; q < 4; ++q) {
            float v = rs[rt][q];
            v += __shfl_xor(v, 1);
            v += __shfl_xor(v, 2);
            v += __shfl_xor(v, 4);
            v += __shfl_xor(v, 8);
            if (frow == 0)
                atomicAdd(&S[256 * ai + wave * 64 + rt * 16 + (lane >> 4) * 4 + q], v);
        }
#undef STAGE
#undef COLBASE
}

// 32 blocks x 256 threads: each thread one row. S[i] already holds the full
// off+on-diagonal exp row sum; subtract fp32 diagonal, log, subtract numerator.
__global__ __launch_bounds__(256) void k_final(
    const float* __restrict__ S, const float* __restrict__ selfdot,
    const float* __restrict__ posdot, float* __restrict__ out)
{
    __shared__ float red[4];
    const int tid = threadIdx.x;
    const int i = blockIdx.x * 256 + tid;
    const float den = fmaxf(S[i] - expf(2.0f * selfdot[i]), 1e-8f);
    float acc = logf(den) - 2.0f * posdot[i];
#pragma unroll
    for (int off = 1; off < 64; off <<= 1) acc += __shfl_xor(acc, off);
    if ((tid & 63) == 0) red[tid >> 6] = acc;
    __syncthreads();
    if (tid == 0)
        atomicAdd(out, (red[0] + red[1] + red[2] + red[3]) * (1.0f / (float)NTOT));
}

extern "C" void kernel_launch(void* const* d_in, const int* in_sizes, int n_in,
                              void* d_out, int out_size, void* d_ws, size_t ws_size,
                              hipStream_t stream) {
    const float* x1 = (const float*)d_in[0];
    const float* x2 = (const float*)d_in[1];
    float* out = (float*)d_out;

    char* ws = (char*)d_ws;
    unsigned short* zbf = (unsigned short*)ws;                       // 4 MB
    size_t off = (size_t)NTOT * DD * sizeof(unsigned short);
    float* S = (float*)(ws + off);                                   // 32 KB
    off += (size_t)NTOT * sizeof(float);
    float* selfdot = (float*)(ws + off);                             // 32 KB
    off += (size_t)NTOT * sizeof(float);
    float* posdot = (float*)(ws + off);                              // 32 KB

    k_normalize<<<dim3(BB / 4), dim3(256), 0, stream>>>(x1, x2, zbf, selfdot, posdot, S, out);
    k_simsum<<<dim3(NBLK), dim3(256), 0, stream>>>(zbf, S);
    k_final<<<dim3(NTOT / 256), dim3(256), 0, stream>>>(S, selfdot, posdot, out);
}